// Round 1
// baseline (251.175 us; speedup 1.0000x reference)
//
#include <hip/hip_runtime.h>

// Full 2D convolution: in (32,16,256,256) f32, shared 5x5 kernel, out (32,16,260,260) f32.
// out[n][y][x] = sum_{a,b in [0,5)} in[n][y-a][x-b] * w[a][b]  (valid in-bounds terms only)
//
// Memory-bound: ~272 MB total traffic -> ~43 us floor at 6.3 TB/s.
// One thread per output float4 (260 = 65 float4 per row, rows 16B-aligned).
// Per thread: 5 rows x 2 float4 loads (clamped addresses, branch-free lane
// zeroing for the two edge threads per row) + 100 FMAs.

#define IMG 256
#define OW  260
#define TXN 65          // float4s per output row
#define NIMG 512        // 32*16 images
#define TOTAL (NIMG * OW * TXN)

__global__ __launch_bounds__(256) void conv_full_kernel(
    const float* __restrict__ in, const float* __restrict__ w,
    float* __restrict__ out)
{
    // Shared 5x5 kernel: uniform loads, keep in registers.
    float wt[25];
#pragma unroll
    for (int i = 0; i < 25; ++i) wt[i] = w[i];

    int idx = blockIdx.x * 256 + threadIdx.x;
    if (idx >= TOTAL) return;

    int tx4 = idx % TXN;        // which float4 within the output row
    int t   = idx / TXN;
    int y   = t % OW;           // output row
    int n   = t / OW;           // image index
    int x0  = tx4 * 4;          // first output column of this thread

    const float* img = in + (size_t)n * IMG * IMG;

    // Clamp the two 16B load addresses into the row; edge lanes get their
    // out-of-image elements zeroed below (branch-free), so clamped junk is discarded.
    int xl = x0 - 4; if (xl < 0) xl = 0;
    int xh = x0;     if (xh > IMG - 4) xh = IMG - 4;
    const bool zL = (tx4 == 0);        // cols x0-4..x0-1 are left of the image
    const bool zR = (tx4 == TXN - 1);  // cols 256..259 are right of the image

    float acc0 = 0.f, acc1 = 0.f, acc2 = 0.f, acc3 = 0.f;

#pragma unroll
    for (int a = 0; a < 5; ++a) {
        int yy = y - a;
        if (yy >= 0 && yy < IMG) {   // wave-uniform for 252/260 rows
            const float* rb = img + yy * IMG;
            float4 lo = *(const float4*)(rb + xl);   // cols x0-4 .. x0-1 (or clamped)
            float4 hi = *(const float4*)(rb + xh);   // cols x0   .. x0+3 (or clamped)
            float v[8];
            v[0] = zL ? 0.f : lo.x;
            v[1] = zL ? 0.f : lo.y;
            v[2] = zL ? 0.f : lo.z;
            v[3] = zL ? 0.f : lo.w;
            v[4] = zR ? 0.f : hi.x;
            v[5] = zR ? 0.f : hi.y;
            v[6] = zR ? 0.f : hi.z;
            v[7] = zR ? 0.f : hi.w;
#pragma unroll
            for (int b = 0; b < 5; ++b) {
                float wv = wt[a * 5 + b];
                // out[x0+c] += v[c+4-b] * w[a][b]
                acc0 = fmaf(v[4 - b], wv, acc0);
                acc1 = fmaf(v[5 - b], wv, acc1);
                acc2 = fmaf(v[6 - b], wv, acc2);
                acc3 = fmaf(v[7 - b], wv, acc3);
            }
        }
    }

    float4 o = make_float4(acc0, acc1, acc2, acc3);
    *(float4*)(out + (size_t)idx * 4) = o;
}

extern "C" void kernel_launch(void* const* d_in, const int* in_sizes, int n_in,
                              void* d_out, int out_size, void* d_ws, size_t ws_size,
                              hipStream_t stream) {
    const float* in = (const float*)d_in[0];   // 32*16*256*256 f32
    const float* w  = (const float*)d_in[1];   // 5*5 f32
    float* out = (float*)d_out;                // 32*16*260*260 f32

    int blocks = (TOTAL + 255) / 256;          // exactly 33800
    conv_full_kernel<<<blocks, 256, 0, stream>>>(in, w, out);
}